// Round 12
// baseline (116.050 us; speedup 1.0000x reference)
//
#include <hip/hip_runtime.h>
#include <hip/hip_bf16.h>

#define DIM 768
#define NTOK 32768
#define TTOK 16
#define NBLK 128

typedef __attribute__((ext_vector_type(8))) short short8;
typedef __attribute__((ext_vector_type(4))) float f32x4;

__device__ __forceinline__ unsigned short f2bf(float f) {
  union { float f; unsigned int u; } v; v.f = f;
  unsigned int u = v.u;
  return (unsigned short)((u + 0x7fffu + ((u >> 16) & 1u)) >> 16);
}
__device__ __forceinline__ float bf2f(unsigned short u) {
  union { unsigned int u; float f; } v; v.u = ((unsigned int)u) << 16; return v.f;
}

// ---- pass 1: per-(block,expert) histogram
__global__ void hist_kernel(const int* __restrict__ mask, int* __restrict__ hist) {
  int tid = threadIdx.x, b = blockIdx.x;
  int gid = b * 256 + tid;
  int wv = tid >> 6, lane = tid & 63;
  int e = mask[gid] & 3;
  __shared__ int wcnt[4][4];
  #pragma unroll
  for (int q = 0; q < 4; ++q) {
    unsigned long long m = __ballot(e == q);
    if (lane == 0) wcnt[wv][q] = __popcll(m);
  }
  __syncthreads();
  if (tid < 4)
    hist[tid * NBLK + b] = wcnt[0][tid] + wcnt[1][tid] + wcnt[2][tid] + wcnt[3][tid];
}

// ---- pass 2: scan + tile starts + dn offsets
__global__ void scan_kernel(const int* __restrict__ hist, int* __restrict__ base,
                            int* __restrict__ meta) {
  int lane = threadIdx.x;  // 64 threads
  int v[8];
  int lsum = 0;
  #pragma unroll
  for (int j = 0; j < 8; ++j) {
    int t = hist[lane * 8 + j];
    v[j] = lsum; lsum += t;
  }
  int inc = lsum;
  #pragma unroll
  for (int d = 1; d < 64; d <<= 1) {
    int u = __shfl_up(inc, d);
    if (lane >= d) inc += u;
  }
  int excl = inc - lsum;
  #pragma unroll
  for (int j = 0; j < 8; ++j) base[lane * 8 + j] = excl + v[j];
  __syncthreads();
  if (lane == 0) {
    int est[5];
    #pragma unroll
    for (int e = 0; e < 4; ++e) est[e] = base[e * NBLK];
    est[4] = NTOK;
    #pragma unroll
    for (int e = 0; e < 5; ++e) meta[e] = est[e];
    int s = 0;
    #pragma unroll
    for (int e = 0; e < 4; ++e) {
      meta[8 + e] = s;
      s += (est[e + 1] - est[e] + TTOK - 1) / TTOK;
    }
    meta[12] = s;
    // dn offsets (in shorts): per expert, tiles*16 rows of KP
    const int KPv[4] = {32, 32, 64, 128};
    int off = 0;
    #pragma unroll
    for (int e = 0; e < 4; ++e) {
      meta[16 + e] = off;
      int tiles = (est[e + 1] - est[e] + TTOK - 1) / TTOK;
      off += tiles * TTOK * KPv[e];
    }
  }
}

// ---- pass 3: scatter tokens to exact sorted positions
__global__ void scatter_kernel(const int* __restrict__ mask, const int* __restrict__ base,
                               int* __restrict__ lists) {
  int tid = threadIdx.x, b = blockIdx.x;
  int gid = b * 256 + tid;
  int wv = tid >> 6, lane = tid & 63;
  int e = mask[gid] & 3;
  __shared__ int wcnt[4][4];
  __shared__ int wbase[4][4];
  unsigned long long lt = (1ull << lane) - 1ull;
  int rank = 0;
  #pragma unroll
  for (int q = 0; q < 4; ++q) {
    unsigned long long m = __ballot(e == q);
    if (e == q) rank = __popcll(m & lt);
    if (lane == 0) wcnt[wv][q] = __popcll(m);
  }
  __syncthreads();
  if (tid < 4) {
    int s = 0;
    #pragma unroll
    for (int w2 = 0; w2 < 4; ++w2) { int c = wcnt[w2][tid]; wbase[w2][tid] = s; s += c; }
  }
  __syncthreads();
  lists[base[e * NBLK + b] + wbase[wv][e] + rank] = gid;
}

// ---- weight repack to bf16 (WdT [ds][768], WuT [768][KP] zero-padded)
__global__ void prep_kernel(const float* __restrict__ Wd0, const float* __restrict__ Wd1,
                            const float* __restrict__ Wd2, const float* __restrict__ Wd3,
                            const float* __restrict__ Wu0, const float* __restrict__ Wu1,
                            const float* __restrict__ Wu2, const float* __restrict__ Wu3,
                            unsigned short* __restrict__ wdT, unsigned short* __restrict__ wuT) {
  int e = blockIdx.x;
  int ds = 16 << e;
  int lgK = (e == 0) ? 5 : (4 + e);
  int KP = 1 << lgK;
  const float* Wd = (e == 0) ? Wd0 : (e == 1) ? Wd1 : (e == 2) ? Wd2 : Wd3;
  const float* Wu = (e == 0) ? Wu0 : (e == 1) ? Wu1 : (e == 2) ? Wu2 : Wu3;
  const int WOFF[4] = {0, 12288, 36864, 86016};
  const int UOFF[4] = {0, 24576, 49152, 98304};
  int stride = gridDim.y * 256;
  int start = blockIdx.y * 256 + threadIdx.x;
  int nd = ds * DIM;
  for (int i = start; i < nd; i += stride) {
    int k = i / DIM, d = i - k * DIM;
    wdT[WOFF[e] + i] = f2bf(Wd[d * ds + k]);
  }
  int nu = DIM << lgK;
  for (int i = start; i < nu; i += stride) {
    int dc = i >> lgK, k = i & (KP - 1);
    wuT[UOFF[e] + i] = (k < ds) ? f2bf(Wu[k * DIM + dc]) : (unsigned short)0;
  }
}

__device__ __forceinline__ int expert_of(int w, const int* __restrict__ ts) {
  return (w >= ts[2]) ? ((w >= ts[3]) ? 3 : 2) : ((w >= ts[1]) ? 1 : 0);
}

// ================= kernel A: down = relu(x @ Wd + bd) -> compact dn =========
template <int E>
__device__ __forceinline__ void down_tile(
    int wv, int lane, int tid, int tile, int cnt,
    const float* __restrict__ x, const int* __restrict__ listsE,
    const unsigned short* __restrict__ wd, const float* __restrict__ bd,
    unsigned short* __restrict__ dnE,
    unsigned short* __restrict__ xs, float* __restrict__ dnpart,
    unsigned short* __restrict__ dnt) {
  constexpr int DS = 16 << E;
  constexpr int KP = (E == 0) ? 32 : DS;
  constexpr int NTA = DS / 16;
  constexpr int SPLIT_N = (NTA < 4) ? NTA : 4;   // 1,2,4,4
  constexpr int SPLIT_K = 4 / SPLIT_N;           // 4,2,1,1
  constexpr int NTB = NTA / SPLIT_N;             // 1,1,1,2
  constexpr int KLEN = DIM / SPLIT_K;            // 192,384,768,768
  int base = tile * TTOK;
  int lrow = lane & 15, kg = lane >> 4;

  // stage this wave's 4 rows as bursts
  #pragma unroll
  for (int i = 0; i < 4; ++i) {
    int rr = base + wv * 4 + i;
    int t = (rr < cnt) ? listsE[rr] : -1;
    int r = wv * 4 + i;
    const float* src = x + (size_t)((t >= 0) ? t : 0) * DIM;
    #pragma unroll
    for (int j = 0; j < 3; ++j) {
      float4 v = {0.f, 0.f, 0.f, 0.f};
      if (t >= 0) v = *(const float4*)(src + j * 256 + lane * 4);
      ushort4 b;
      b.x = f2bf(v.x); b.y = f2bf(v.y); b.z = f2bf(v.z); b.w = f2bf(v.w);
      *(ushort4*)(xs + r * 776 + j * 256 + lane * 4) = b;
    }
  }
  if (SPLIT_K > 1) {
    for (int i = tid; i < TTOK * DS; i += 256) dnpart[i] = 0.f;
  }
  __syncthreads();

  int nsub = wv % SPLIT_N, ksub = wv / SPLIT_N;
  int d_base = ksub * KLEN;
  f32x4 acc[NTB];
  #pragma unroll
  for (int nb = 0; nb < NTB; ++nb) acc[nb] = f32x4{0.f, 0.f, 0.f, 0.f};

  for (int d0 = 0; d0 < KLEN; d0 += 64) {
    #pragma unroll
    for (int u = 0; u < 2; ++u) {
      int d = d_base + d0 + u * 32;
      short8 a = *(const short8*)(xs + lrow * 776 + d + kg * 8);
      #pragma unroll
      for (int nb = 0; nb < NTB; ++nb) {
        int n = nsub * NTB + nb;
        short8 b = *(const short8*)(wd + (size_t)(n * 16 + lrow) * DIM + d + kg * 8);
        acc[nb] = __builtin_amdgcn_mfma_f32_16x16x32_bf16(a, b, acc[nb], 0, 0, 0);
      }
    }
  }

  if (SPLIT_K > 1) {
    int kc = nsub * 16 + lrow;   // NTB==1 here
    #pragma unroll
    for (int r = 0; r < 4; ++r)
      atomicAdd(&dnpart[(kg * 4 + r) * DS + kc], acc[0][r]);
    __syncthreads();
    for (int i = tid; i < TTOK * KP; i += 256) {
      int tt = i / KP, k = i - tt * KP;
      float v = (k < DS) ? fmaxf(dnpart[tt * DS + k] + bd[k], 0.f) : 0.f;
      dnt[tt * KP + k] = f2bf(v);
    }
  } else {
    #pragma unroll
    for (int nb = 0; nb < NTB; ++nb) {
      int kc = (nsub * NTB + nb) * 16 + lrow;
      float bv = bd[kc];
      #pragma unroll
      for (int r = 0; r < 4; ++r)
        dnt[(kg * 4 + r) * KP + kc] = f2bf(fmaxf(acc[nb][r] + bv, 0.f));
    }
  }
  __syncthreads();

  // burst-copy dn tile to compact global [row][KP]
  unsigned short* dst = dnE + (size_t)base * KP;
  constexpr int S = TTOK * KP;
  for (int i = tid * 8; i < S; i += 256 * 8)
    *(int4*)(dst + i) = *(const int4*)(dnt + i);
}

__global__ __launch_bounds__(256, 5) void down_main(
    const float* __restrict__ x,
    const int* __restrict__ meta, const int* __restrict__ lists,
    const unsigned short* __restrict__ wdT,
    const float* __restrict__ bd0, const float* __restrict__ bd1,
    const float* __restrict__ bd2, const float* __restrict__ bd3,
    unsigned short* __restrict__ dnc) {
  __shared__ unsigned short xs[TTOK * 776];
  __shared__ float dnpart[TTOK * 32];
  __shared__ unsigned short dnt[TTOK * 128];
  int tid = threadIdx.x, wv = tid >> 6, lane = tid & 63;
  const int* ts = meta + 8;
  int w = blockIdx.x;
  if (w >= ts[4]) return;
  int e = expert_of(w, ts);
  int tile = w - ts[e];
  int cnt = meta[e + 1] - meta[e];
  const int* listsE = lists + meta[e];
  const int WOFF[4] = {0, 12288, 36864, 86016};
  unsigned short* dnE = dnc + meta[16 + e];
  if (e == 0)
    down_tile<0>(wv, lane, tid, tile, cnt, x, listsE, wdT + WOFF[0], bd0, dnE, xs, dnpart, dnt);
  else if (e == 1)
    down_tile<1>(wv, lane, tid, tile, cnt, x, listsE, wdT + WOFF[1], bd1, dnE, xs, dnpart, dnt);
  else if (e == 2)
    down_tile<2>(wv, lane, tid, tile, cnt, x, listsE, wdT + WOFF[2], bd2, dnE, xs, dnpart, dnt);
  else
    down_tile<3>(wv, lane, tid, tile, cnt, x, listsE, wdT + WOFF[3], bd3, dnE, xs, dnpart, dnt);
}

// ================= kernel B: up = dn @ Wu + bu + x -> out ====================
template <int E>
__device__ __forceinline__ void up_tile(
    int wv, int lane, int tid, int tile, int cnt,
    const float* __restrict__ x, const int* __restrict__ listsE,
    const unsigned short* __restrict__ wu, const float* __restrict__ bu,
    const unsigned short* __restrict__ dnE, float* __restrict__ out,
    unsigned short* __restrict__ OL) {
  constexpr int DS = 16 << E;
  constexpr int KP = (E == 0) ? 32 : DS;
  constexpr int KB = KP / 32;
  int base = tile * TTOK;
  int lrow = lane & 15, kg = lane >> 4;

  // A-fragments: contiguous compact dn rows (no indirection)
  short8 afr[KB];
  const unsigned short* dsrc = dnE + (size_t)(base + lrow) * KP + kg * 8;
  #pragma unroll
  for (int k = 0; k < KB; ++k) afr[k] = *(const short8*)(dsrc + k * 32);

  #pragma unroll 3
  for (int nn = 0; nn < 12; ++nn) {
    int n = wv * 12 + nn;
    f32x4 c = {0.f, 0.f, 0.f, 0.f};
    #pragma unroll
    for (int k = 0; k < KB; ++k) {
      short8 b = *(const short8*)(wu + (size_t)(n * 16 + lrow) * KP + k * 32 + kg * 8);
      c = __builtin_amdgcn_mfma_f32_16x16x32_bf16(afr[k], b, c, 0, 0, 0);
    }
    int dcol = n * 16 + lrow;
    float bv = bu[dcol];
    #pragma unroll
    for (int r = 0; r < 4; ++r)
      OL[(kg * 4 + r) * 772 + dcol] = f2bf(c[r] + bv);
  }
  __syncthreads();

  // epilogue: wave's 4 rows: out = OL + x (f32 residual), burst
  #pragma unroll
  for (int i = 0; i < 4; ++i) {
    int r = wv * 4 + i;
    int gr = base + r;
    int t = (gr < cnt) ? listsE[gr] : -1;
    if (t < 0) continue;
    const float* xsrc = x + (size_t)t * DIM;
    float* dst = out + (size_t)t * DIM;
    #pragma unroll
    for (int j = 0; j < 3; ++j) {
      int c4 = j * 256 + lane * 4;
      float4 xv = *(const float4*)(xsrc + c4);
      ushort4 ub = *(const ushort4*)(OL + r * 772 + c4);
      float4 o;
      o.x = xv.x + bf2f(ub.x);
      o.y = xv.y + bf2f(ub.y);
      o.z = xv.z + bf2f(ub.z);
      o.w = xv.w + bf2f(ub.w);
      *(float4*)(dst + c4) = o;
    }
  }
}

__global__ __launch_bounds__(256, 6) void up_main(
    const float* __restrict__ x,
    const int* __restrict__ meta, const int* __restrict__ lists,
    const unsigned short* __restrict__ wuT,
    const float* __restrict__ bu0, const float* __restrict__ bu1,
    const float* __restrict__ bu2, const float* __restrict__ bu3,
    const unsigned short* __restrict__ dnc, float* __restrict__ out) {
  __shared__ unsigned short OL[TTOK * 772];
  int tid = threadIdx.x, wv = tid >> 6, lane = tid & 63;
  const int* ts = meta + 8;
  int w = blockIdx.x;
  if (w >= ts[4]) return;
  int e = expert_of(w, ts);
  int tile = w - ts[e];
  int cnt = meta[e + 1] - meta[e];
  const int* listsE = lists + meta[e];
  const int UOFF[4] = {0, 24576, 49152, 98304};
  const unsigned short* dnE = dnc + meta[16 + e];
  if (e == 0)
    up_tile<0>(wv, lane, tid, tile, cnt, x, listsE, wuT + UOFF[0], bu0, dnE, out, OL);
  else if (e == 1)
    up_tile<1>(wv, lane, tid, tile, cnt, x, listsE, wuT + UOFF[1], bu1, dnE, out, OL);
  else if (e == 2)
    up_tile<2>(wv, lane, tid, tile, cnt, x, listsE, wuT + UOFF[2], bu2, dnE, out, OL);
  else
    up_tile<3>(wv, lane, tid, tile, cnt, x, listsE, wuT + UOFF[3], bu3, dnE, out, OL);
}

extern "C" void kernel_launch(void* const* d_in, const int* in_sizes, int n_in,
                              void* d_out, int out_size, void* d_ws, size_t ws_size,
                              hipStream_t stream) {
  const float* x = (const float*)d_in[0];
  const int* mask = (const int*)d_in[1];
  const float* Wd[4]; const float* bd[4]; const float* Wu[4]; const float* bu[4];
  for (int i = 0; i < 4; ++i) {
    Wd[i] = (const float*)d_in[2 + 4 * i];
    bd[i] = (const float*)d_in[3 + 4 * i];
    Wu[i] = (const float*)d_in[4 + 4 * i];
    bu[i] = (const float*)d_in[5 + 4 * i];
  }
  char* ws = (char*)d_ws;
  int* hist = (int*)ws;                                  // 2048 B
  int* base = (int*)(ws + 2048);                         // 2048 B
  int* meta = (int*)(ws + 4096);                         // 128 B
  int* lists = (int*)(ws + 4352);                        // 131072 B
  unsigned short* wdT = (unsigned short*)(ws + 135424);  // 368640 B
  unsigned short* wuT = (unsigned short*)(ws + 504064);  // 393216 B
  unsigned short* dnc = (unsigned short*)(ws + 897280);  // <= ~8.4 MB (actual ~4.3 MB)

  hist_kernel<<<NBLK, 256, 0, stream>>>(mask, hist);
  scan_kernel<<<1, 64, 0, stream>>>(hist, base, meta);
  scatter_kernel<<<NBLK, 256, 0, stream>>>(mask, base, lists);
  prep_kernel<<<dim3(4, 32), 256, 0, stream>>>(Wd[0], Wd[1], Wd[2], Wd[3],
                                               Wu[0], Wu[1], Wu[2], Wu[3], wdT, wuT);
  down_main<<<2051, 256, 0, stream>>>(x, meta, lists, wdT,
                                      bd[0], bd[1], bd[2], bd[3], dnc);
  up_main<<<2051, 256, 0, stream>>>(x, meta, lists, wuT,
                                    bu[0], bu[1], bu[2], bu[3], dnc,
                                    (float*)d_out);
}

// Round 13
// 100.791 us; speedup vs baseline: 1.1514x; 1.1514x over previous
//
#include <hip/hip_runtime.h>
#include <hip/hip_bf16.h>

#define DIM 768
#define NTOK 32768
#define TTOK 16
#define NBLK 128
#define GMAIN 512

typedef __attribute__((ext_vector_type(8))) short short8;
typedef __attribute__((ext_vector_type(4))) float f32x4;

__device__ __forceinline__ unsigned short f2bf(float f) {
  union { float f; unsigned int u; } v; v.f = f;
  unsigned int u = v.u;
  return (unsigned short)((u + 0x7fffu + ((u >> 16) & 1u)) >> 16);
}
__device__ __forceinline__ float bf2f(unsigned short u) {
  union { unsigned int u; float f; } v; v.u = ((unsigned int)u) << 16; return v.f;
}

// ---- pass 1: per-(block,expert) histogram
__global__ void hist_kernel(const int* __restrict__ mask, int* __restrict__ hist) {
  int tid = threadIdx.x, b = blockIdx.x;
  int gid = b * 256 + tid;
  int wv = tid >> 6, lane = tid & 63;
  int e = mask[gid] & 3;
  __shared__ int wcnt[4][4];
  #pragma unroll
  for (int q = 0; q < 4; ++q) {
    unsigned long long m = __ballot(e == q);
    if (lane == 0) wcnt[wv][q] = __popcll(m);
  }
  __syncthreads();
  if (tid < 4)
    hist[tid * NBLK + b] = wcnt[0][tid] + wcnt[1][tid] + wcnt[2][tid] + wcnt[3][tid];
}

// ---- pass 2: scan + tile starts
__global__ void scan_kernel(const int* __restrict__ hist, int* __restrict__ base,
                            int* __restrict__ meta) {
  int lane = threadIdx.x;  // 64 threads
  int v[8];
  int lsum = 0;
  #pragma unroll
  for (int j = 0; j < 8; ++j) {
    int t = hist[lane * 8 + j];
    v[j] = lsum; lsum += t;
  }
  int inc = lsum;
  #pragma unroll
  for (int d = 1; d < 64; d <<= 1) {
    int u = __shfl_up(inc, d);
    if (lane >= d) inc += u;
  }
  int excl = inc - lsum;
  #pragma unroll
  for (int j = 0; j < 8; ++j) base[lane * 8 + j] = excl + v[j];
  __syncthreads();
  if (lane == 0) {
    int est[5];
    #pragma unroll
    for (int e = 0; e < 4; ++e) est[e] = base[e * NBLK];
    est[4] = NTOK;
    #pragma unroll
    for (int e = 0; e < 5; ++e) meta[e] = est[e];
    int s = 0;
    #pragma unroll
    for (int e = 0; e < 4; ++e) {
      meta[8 + e] = s;
      s += (est[e + 1] - est[e] + TTOK - 1) / TTOK;
    }
    meta[12] = s;
  }
}

// ---- pass 3: scatter tokens to exact sorted positions
__global__ void scatter_kernel(const int* __restrict__ mask, const int* __restrict__ base,
                               int* __restrict__ lists) {
  int tid = threadIdx.x, b = blockIdx.x;
  int gid = b * 256 + tid;
  int wv = tid >> 6, lane = tid & 63;
  int e = mask[gid] & 3;
  __shared__ int wcnt[4][4];
  __shared__ int wbase[4][4];
  unsigned long long lt = (1ull << lane) - 1ull;
  int rank = 0;
  #pragma unroll
  for (int q = 0; q < 4; ++q) {
    unsigned long long m = __ballot(e == q);
    if (e == q) rank = __popcll(m & lt);
    if (lane == 0) wcnt[wv][q] = __popcll(m);
  }
  __syncthreads();
  if (tid < 4) {
    int s = 0;
    #pragma unroll
    for (int w2 = 0; w2 < 4; ++w2) { int c = wcnt[w2][tid]; wbase[w2][tid] = s; s += c; }
  }
  __syncthreads();
  lists[base[e * NBLK + b] + wbase[wv][e] + rank] = gid;
}

// ---- weight repack to bf16 (WdT [ds][768], WuT [768][KP] zero-padded)
__global__ void prep_kernel(const float* __restrict__ Wd0, const float* __restrict__ Wd1,
                            const float* __restrict__ Wd2, const float* __restrict__ Wd3,
                            const float* __restrict__ Wu0, const float* __restrict__ Wu1,
                            const float* __restrict__ Wu2, const float* __restrict__ Wu3,
                            unsigned short* __restrict__ wdT, unsigned short* __restrict__ wuT) {
  int e = blockIdx.x;
  int ds = 16 << e;
  int lgK = (e == 0) ? 5 : (4 + e);
  int KP = 1 << lgK;
  const float* Wd = (e == 0) ? Wd0 : (e == 1) ? Wd1 : (e == 2) ? Wd2 : Wd3;
  const float* Wu = (e == 0) ? Wu0 : (e == 1) ? Wu1 : (e == 2) ? Wu2 : Wu3;
  const int WOFF[4] = {0, 12288, 36864, 86016};
  const int UOFF[4] = {0, 24576, 49152, 98304};
  int stride = gridDim.y * 256;
  int start = blockIdx.y * 256 + threadIdx.x;
  int nd = ds * DIM;
  for (int i = start; i < nd; i += stride) {
    int k = i / DIM, d = i - k * DIM;
    wdT[WOFF[e] + i] = f2bf(Wd[d * ds + k]);
  }
  int nu = DIM << lgK;
  for (int i = start; i < nu; i += stride) {
    int dc = i >> lgK, k = i & (KP - 1);
    wuT[UOFF[e] + i] = (k < ds) ? f2bf(Wu[k * DIM + dc]) : (unsigned short)0;
  }
}

__device__ __forceinline__ int expert_of(int w, const int* __restrict__ ts) {
  return (w >= ts[2]) ? ((w >= ts[3]) ? 3 : 2) : ((w >= ts[1]) ? 1 : 0);
}

// ---- DOWN crew, SEG2: GEMM1 from xs (R6 phase-A body)
template <int E>
__device__ __forceinline__ void down_g1(
    int cwv, int lane,
    const unsigned short* __restrict__ wd, const float* __restrict__ bd,
    const unsigned short* __restrict__ xs, float* __restrict__ dnpart,
    unsigned short (*dnc)[136]) {
  constexpr int DS = 16 << E;
  constexpr int NTA = DS / 16;
  constexpr int SPLIT_N = (NTA < 4) ? NTA : 4;   // 1,2,4,4
  constexpr int SPLIT_K = 4 / SPLIT_N;           // 4,2,1,1
  constexpr int NTB = NTA / SPLIT_N;             // 1,1,1,2
  constexpr int KLEN = DIM / SPLIT_K;            // 192,384,768,768
  int lrow = lane & 15, kg = lane >> 4;
  int nsub = cwv % SPLIT_N, ksub = cwv / SPLIT_N;
  int d_base = ksub * KLEN;

  f32x4 acc[NTB];
  #pragma unroll
  for (int nb = 0; nb < NTB; ++nb) acc[nb] = f32x4{0.f, 0.f, 0.f, 0.f};

  for (int d0 = 0; d0 < KLEN; d0 += 64) {
    #pragma unroll
    for (int u = 0; u < 2; ++u) {
      int d = d_base + d0 + u * 32;
      short8 a = *(const short8*)(xs + lrow * 776 + d + kg * 8);
      #pragma unroll
      for (int nb = 0; nb < NTB; ++nb) {
        int n = nsub * NTB + nb;
        short8 b = *(const short8*)(wd + (size_t)(n * 16 + lrow) * DIM + d + kg * 8);
        acc[nb] = __builtin_amdgcn_mfma_f32_16x16x32_bf16(a, b, acc[nb], 0, 0, 0);
      }
    }
  }

  if (SPLIT_K > 1) {
    int kc = nsub * 16 + lrow;   // NTB==1 here
    #pragma unroll
    for (int r = 0; r < 4; ++r)
      atomicAdd(&dnpart[(kg * 4 + r) * DS + kc], acc[0][r]);
  } else {
    #pragma unroll
    for (int nb = 0; nb < NTB; ++nb) {
      int kc = (nsub * NTB + nb) * 16 + lrow;
      float bv = bd[kc];
      #pragma unroll
      for (int r = 0; r < 4; ++r)
        dnc[kg * 4 + r][kc] = f2bf(fmaxf(acc[nb][r] + bv, 0.f));
    }
  }
}

// ---- UP crew, SEG1: GEMM2 from dn[pb] -> OL (R12 up body, LDS dn)
template <int E>
__device__ __forceinline__ void up_g2(
    int cwv, int lane,
    const unsigned short* __restrict__ wu, const float* __restrict__ bu,
    const unsigned short (*dnp)[136], unsigned short* __restrict__ OL) {
  constexpr int KP = (E == 0) ? 32 : (16 << E);
  constexpr int KB = KP / 32;
  int lrow = lane & 15, kg = lane >> 4;
  short8 afr[KB];
  #pragma unroll
  for (int k = 0; k < KB; ++k) afr[k] = *(const short8*)&dnp[lrow][k * 32 + kg * 8];

  #pragma unroll 3
  for (int nn = 0; nn < 12; ++nn) {
    int n = cwv * 12 + nn;
    f32x4 c = {0.f, 0.f, 0.f, 0.f};
    #pragma unroll
    for (int k = 0; k < KB; ++k) {
      short8 b = *(const short8*)(wu + (size_t)(n * 16 + lrow) * KP + k * 32 + kg * 8);
      c = __builtin_amdgcn_mfma_f32_16x16x32_bf16(afr[k], b, c, 0, 0, 0);
    }
    int dcol = n * 16 + lrow;
    float bv = bu[dcol];
    #pragma unroll
    for (int r = 0; r < 4; ++r)
      OL[(kg * 4 + r) * 772 + dcol] = f2bf(c[r] + bv);
  }
}

// ---- fused producer/consumer: 4 DOWN waves pipeline GEMM1(tile i) against
// 4 UP waves doing GEMM2+store(tile i-1). dn double-buffered in LDS.
__global__ __launch_bounds__(512, 4) void moe_main(
    const float* __restrict__ x,
    const int* __restrict__ meta, const int* __restrict__ lists,
    const unsigned short* __restrict__ wdT, const unsigned short* __restrict__ wuT,
    const float* __restrict__ bd0, const float* __restrict__ bd1,
    const float* __restrict__ bd2, const float* __restrict__ bd3,
    const float* __restrict__ bu0, const float* __restrict__ bu1,
    const float* __restrict__ bu2, const float* __restrict__ bu3,
    float* __restrict__ out) {
  __shared__ unsigned short xs[TTOK * 776];       // 24832 B
  __shared__ unsigned short dnb[2][TTOK][136];    //  8704 B
  __shared__ float dnpart[TTOK * 32];             //  2048 B
  __shared__ unsigned short OL[TTOK * 772];       // 24704 B
  __shared__ int toksL[2][TTOK];                  //   128 B

  int tid = threadIdx.x, wv = tid >> 6, lane = tid & 63;
  bool dcrew = wv < 4;
  int cwv = wv & 3;
  int ctid = tid & 255;
  const int* ts = meta + 8;
  int ntiles = ts[4];
  int w0 = blockIdx.x;
  if (w0 >= ntiles) return;
  int ntb = (ntiles - 1 - w0) / GMAIN + 1;

  if (dcrew) for (int i = ctid; i < TTOK * 32; i += 256) dnpart[i] = 0.f;

  const int WOFF[4] = {0, 12288, 36864, 86016};
  const int UOFF[4] = {0, 24576, 49152, 98304};
  const float* bds[4] = {bd0, bd1, bd2, bd3};
  const float* bus[4] = {bu0, bu1, bu2, bu3};

  for (int i = 0; i <= ntb; ++i) {
    bool hasC = i < ntb, hasP = i > 0;
    int cb = i & 1, pb = cb ^ 1;
    int ec = 0, basec = 0, cntc = 0;
    const int* listsC = lists;
    if (hasC) {
      int wc = w0 + i * GMAIN;
      ec = expert_of(wc, ts);
      basec = (wc - ts[ec]) * TTOK;
      cntc = meta[ec + 1] - meta[ec];
      listsC = lists + meta[ec];
    }
    int ep = 0;
    if (hasP) ep = expert_of(w0 + (i - 1) * GMAIN, ts);
    bool esplit = hasC && (ec <= 1);

    // ================= SEG1: DOWN stages xs[tile i] | UP GEMM2 -> OL =======
    if (dcrew) {
      if (hasC) {
        int myt[4];
        #pragma unroll
        for (int j = 0; j < 4; ++j) {
          int r = basec + cwv * 4 + j;
          myt[j] = (r < cntc) ? listsC[r] : -1;
        }
        if (ctid < TTOK)
          toksL[cb][ctid] = (basec + ctid < cntc) ? listsC[basec + ctid] : -1;
        #pragma unroll
        for (int j = 0; j < 4; ++j) {
          int r = cwv * 4 + j;
          int t = myt[j];
          const float* src = x + (size_t)((t >= 0) ? t : 0) * DIM;
          #pragma unroll
          for (int c = 0; c < 3; ++c) {
            float4 v = {0.f, 0.f, 0.f, 0.f};
            if (t >= 0) v = *(const float4*)(src + c * 256 + lane * 4);
            ushort4 b;
            b.x = f2bf(v.x); b.y = f2bf(v.y); b.z = f2bf(v.z); b.w = f2bf(v.w);
            *(ushort4*)(xs + r * 776 + c * 256 + lane * 4) = b;
          }
        }
      }
    } else if (hasP) {
      const unsigned short* wu = wuT + UOFF[ep];
      const float* bu = bus[ep];
      if (ep == 0)      up_g2<0>(cwv, lane, wu, bu, dnb[pb], OL);
      else if (ep == 1) up_g2<1>(cwv, lane, wu, bu, dnb[pb], OL);
      else if (ep == 2) up_g2<2>(cwv, lane, wu, bu, dnb[pb], OL);
      else              up_g2<3>(cwv, lane, wu, bu, dnb[pb], OL);
    }
    __syncthreads();

    // ================= SEG2: DOWN GEMM1 | UP burst-store out ===============
    if (dcrew) {
      if (hasC) {
        const unsigned short* wd = wdT + WOFF[ec];
        const float* bd = bds[ec];
        if (ec == 0)      down_g1<0>(cwv, lane, wd, bd, xs, dnpart, dnb[cb]);
        else if (ec == 1) down_g1<1>(cwv, lane, wd, bd, xs, dnpart, dnb[cb]);
        else if (ec == 2) down_g1<2>(cwv, lane, wd, bd, xs, dnpart, dnb[cb]);
        else              down_g1<3>(cwv, lane, wd, bd, xs, dnpart, dnb[cb]);
      }
    } else if (hasP) {
      #pragma unroll
      for (int j = 0; j < 4; ++j) {
        int r = cwv * 4 + j;
        int t = toksL[pb][r];
        if (t < 0) continue;
        const float* xsrc = x + (size_t)t * DIM;
        float* dst = out + (size_t)t * DIM;
        #pragma unroll
        for (int c = 0; c < 3; ++c) {
          int c4 = c * 256 + lane * 4;
          float4 xv = *(const float4*)(xsrc + c4);
          ushort4 ub = *(const ushort4*)(OL + r * 772 + c4);
          float4 o;
          o.x = xv.x + bf2f(ub.x);
          o.y = xv.y + bf2f(ub.y);
          o.z = xv.z + bf2f(ub.z);
          o.w = xv.w + bf2f(ub.w);
          *(float4*)(dst + c4) = o;
        }
      }
    }

    // extra step only for SPLIT_K experts (uniform decision block-wide)
    if (esplit) {
      __syncthreads();
      if (dcrew) {
        const float* bd = bds[ec];
        int DS = (ec == 0) ? 16 : 32;
        for (int ii = ctid; ii < TTOK * 32; ii += 256) {
          int tt = ii >> 5, k = ii & 31;
          float v = 0.f;
          if (k < DS) {
            v = fmaxf(dnpart[tt * DS + k] + bd[k], 0.f);
            dnpart[tt * DS + k] = 0.f;   // re-zero for next SPLIT_K tile
          }
          dnb[cb][tt][k] = f2bf(v);
        }
      }
    }
    __syncthreads();   // publishes dn[cb]; xs/OL safe to reuse
  }
}

extern "C" void kernel_launch(void* const* d_in, const int* in_sizes, int n_in,
                              void* d_out, int out_size, void* d_ws, size_t ws_size,
                              hipStream_t stream) {
  const float* x = (const float*)d_in[0];
  const int* mask = (const int*)d_in[1];
  const float* Wd[4]; const float* bd[4]; const float* Wu[4]; const float* bu[4];
  for (int i = 0; i < 4; ++i) {
    Wd[i] = (const float*)d_in[2 + 4 * i];
    bd[i] = (const float*)d_in[3 + 4 * i];
    Wu[i] = (const float*)d_in[4 + 4 * i];
    bu[i] = (const float*)d_in[5 + 4 * i];
  }
  char* ws = (char*)d_ws;
  int* hist = (int*)ws;                                  // 2048 B
  int* base = (int*)(ws + 2048);                         // 2048 B
  int* meta = (int*)(ws + 4096);                         // 128 B
  int* lists = (int*)(ws + 4352);                        // 131072 B
  unsigned short* wdT = (unsigned short*)(ws + 135424);  // 368640 B
  unsigned short* wuT = (unsigned short*)(ws + 504064);  // 393216 B

  hist_kernel<<<NBLK, 256, 0, stream>>>(mask, hist);
  scan_kernel<<<1, 64, 0, stream>>>(hist, base, meta);
  scatter_kernel<<<NBLK, 256, 0, stream>>>(mask, base, lists);
  prep_kernel<<<dim3(4, 32), 256, 0, stream>>>(Wd[0], Wd[1], Wd[2], Wd[3],
                                               Wu[0], Wu[1], Wu[2], Wu[3], wdT, wuT);
  moe_main<<<GMAIN, 512, 0, stream>>>(x, meta, lists, wdT, wuT,
                                      bd[0], bd[1], bd[2], bd[3],
                                      bu[0], bu[1], bu[2], bu[3],
                                      (float*)d_out);
}